// Round 3
// baseline (332.029 us; speedup 1.0000x reference)
//
#include <hip/hip_runtime.h>
#include <hip/hip_bf16.h>

// MultiHeadedAttention2: dual-stream MHA with elementwise-max merge of the two
// softmax attention maps. Inputs fp32 (detected & converted to bf16 in ws);
// internal compute bf16 MFMA; OUTPUT WRITTEN AS FP32 (reference output dtype).
//
// Pipeline (4 dispatches):
//  0) convert_inputs: probe each tensor (bf16-view of first 512 elems; fp32
//     bits viewed as bf16 show >1e4/NaN values), convert/copy to bf16 in ws.
//  1) qkv_gemm : 6 projections. Q,K -> [B,H,S,64] bf16, V -> [B,H,64,S] bf16.
//                Q pre-scaled by 0.125*log2(e) so softmax uses native v_exp_f32.
//  2) attn_merged: two-pass merged softmax (pass1 row sums, pass2 recompute +
//                max-merge + PV), O -> [B,S,512] bf16 in ws.
//  3) out_gemm : output projections + bias -> d_out (FP32, rgb then flow).

typedef unsigned short u16;
typedef __attribute__((ext_vector_type(8))) short short8;   // 8 x bf16 (4 VGPRs)
typedef __attribute__((ext_vector_type(4))) float floatx4;  // MFMA accumulator

#define B_DIM 8
#define S_DIM 1024
#define H_DIM 8
#define DK 64
#define DMODEL 512
#define NTOK (B_DIM * S_DIM)                 // 8192 tokens
#define SEG ((size_t)NTOK * DMODEL)          // 4194304 elems per tensor
#define WSEG ((size_t)DMODEL * DMODEL)       // 262144 elems per weight

__device__ __forceinline__ floatx4 mfma_bf16(short8 a, short8 b, floatx4 c) {
  return __builtin_amdgcn_mfma_f32_16x16x32_bf16(a, b, c, 0, 0, 0);
}

__device__ __forceinline__ u16 f32_to_bf16_rne(float f) {
  unsigned u = __float_as_uint(f);
  unsigned r = u + 0x7FFFu + ((u >> 16) & 1u);
  return (u16)(r >> 16);
}

__device__ __forceinline__ float bf16_bits_to_f32(u16 u) {
  return __uint_as_float(((unsigned)u) << 16);
}

// async global->LDS, 16B per lane; lds is the wave-uniform base
// (HW deposits lane i at lds + i*16).
__device__ __forceinline__ void async_cp16(const u16* g, u16* lds) {
  __builtin_amdgcn_global_load_lds(
      (__attribute__((address_space(1))) void*)(const_cast<u16*>(g)),
      (__attribute__((address_space(3))) void*)(lds), 16, 0, 0);
}

// ---------------------------------------------------------------------------
// Kernel 0: dtype-detect + convert to bf16. Each block handles one 65536-elem
// chunk of one tensor; wave 0 probes the tensor's first 512 elems (bf16 view)
// to decide fp32 vs bf16 (deterministic, same verdict for all blocks).
// ---------------------------------------------------------------------------
#define NT_CONV 18
struct ConvParams {
  const void* src[NT_CONV];
  u16* dst[NT_CONV];
  int n[NT_CONV];
  int coff[NT_CONV + 1];   // prefix sums of chunk counts
};

__global__ __launch_bounds__(256) void convert_inputs(ConvParams p) {
  __shared__ int flag_f32;
  const int blk = blockIdx.x;
  int t = 0;
  while (t + 1 < NT_CONV && blk >= p.coff[t + 1]) ++t;
  const int lc = blk - p.coff[t];
  const int n = p.n[t];
  const int tid = threadIdx.x;

  if (tid < 64) {
    const u16* s = (const u16*)p.src[t];
    int bad = 0;
#pragma unroll
    for (int j = 0; j < 8; ++j) {
      float f = bf16_bits_to_f32(s[tid * 8 + j]);
      bad |= !(fabsf(f) < 1e4f);   // catches huge AND NaN
    }
    bad |= __shfl_xor(bad, 1);
    bad |= __shfl_xor(bad, 2);
    bad |= __shfl_xor(bad, 4);
    bad |= __shfl_xor(bad, 8);
    bad |= __shfl_xor(bad, 16);
    bad |= __shfl_xor(bad, 32);
    if (tid == 0) flag_f32 = bad;
  }
  __syncthreads();
  const int is_f32 = flag_f32;
  const int base = lc * 65536;

  for (int it = 0; it < 32; ++it) {
    const int idx = base + (it * 256 + tid) * 8;
    if (idx + 8 > n) break;
    if (!is_f32) {
      *(short8*)&p.dst[t][idx] = *(const short8*)&((const u16*)p.src[t])[idx];
    } else {
      const float* s = (const float*)p.src[t] + idx;
      short8 o;
#pragma unroll
      for (int j = 0; j < 8; ++j) o[j] = (short)f32_to_bf16_rne(s[j]);
      *(short8*)&p.dst[t][idx] = o;
    }
  }
}

// ---------------------------------------------------------------------------
// 128x128 NT GEMM mainloop: C += A[m0:+128, :K] * W[n0:+128, :K]^T
// A,W row-major bf16, lda = ldw = K. 256 threads / 4 waves (2x2), each wave a
// 64x64 sub-tile as 4x4 mfma_f32_16x16x32_bf16. Single-buffer LDS (m97-style),
// global_load_lds width=16 staging.
// ---------------------------------------------------------------------------
__device__ __forceinline__ void gemm128_mainloop(
    const u16* __restrict__ A, const u16* __restrict__ W,
    int m0, int n0, int K, u16* ldsA, u16* ldsB, floatx4 acc[4][4]) {
  const int tid = threadIdx.x;
  const int lane = tid & 63;
  const int wid = tid >> 6;
  const int wm = wid >> 1, wn = wid & 1;
  const int r = lane & 15, g = lane >> 4;

  const int stg_row = wid * 32 + (lane >> 2);
  const int stg_col = (lane & 3) * 8;

  const u16* ga0 = A + (size_t)(m0 + stg_row) * K + stg_col;
  const u16* ga1 = A + (size_t)(m0 + stg_row + 16) * K + stg_col;
  const u16* gb0 = W + (size_t)(n0 + stg_row) * K + stg_col;
  const u16* gb1 = W + (size_t)(n0 + stg_row + 16) * K + stg_col;
  u16* la0 = ldsA + (wid * 32) * 32;       // wave-uniform LDS bases
  u16* la1 = ldsA + (wid * 32 + 16) * 32;
  u16* lb0 = ldsB + (wid * 32) * 32;
  u16* lb1 = ldsB + (wid * 32 + 16) * 32;

  for (int k0 = 0; k0 < K; k0 += 32) {
    if (k0) __syncthreads();                  // protect LDS from prev readers
    async_cp16(ga0 + k0, la0);
    async_cp16(ga1 + k0, la1);
    async_cp16(gb0 + k0, lb0);
    async_cp16(gb1 + k0, lb1);
    __syncthreads();                          // drains vmcnt before ds_read

    short8 a[4], b[4];
#pragma unroll
    for (int i = 0; i < 4; ++i)
      a[i] = *(const short8*)&ldsA[(wm * 64 + i * 16 + r) * 32 + g * 8];
#pragma unroll
    for (int j = 0; j < 4; ++j)
      b[j] = *(const short8*)&ldsB[(wn * 64 + j * 16 + r) * 32 + g * 8];
#pragma unroll
    for (int i = 0; i < 4; ++i)
#pragma unroll
      for (int j = 0; j < 4; ++j)
        acc[i][j] = mfma_bf16(a[i], b[j], acc[i][j]);
  }
}

// ---------------------------------------------------------------------------
// Kernel 1: QKV projections. grid = (64, 12, 2).
// ---------------------------------------------------------------------------
struct QkvParams {
  const u16* X[2];
  const u16* W[2][3];
  const u16* Bias[2][3];
  u16* Out[2][3];
};

__global__ __launch_bounds__(256) void qkv_gemm(QkvParams p) {
  __shared__ u16 ldsA[128 * 32];
  __shared__ u16 ldsB[128 * 32];
  const int z = blockIdx.z;
  const int wi = blockIdx.y >> 2;            // 0=Q 1=K 2=V
  const int n0 = (blockIdx.y & 3) * 128;
  const int m0 = blockIdx.x * 128;

  floatx4 acc[4][4];
  const floatx4 z4 = {0.f, 0.f, 0.f, 0.f};
#pragma unroll
  for (int i = 0; i < 4; ++i)
#pragma unroll
    for (int j = 0; j < 4; ++j) acc[i][j] = z4;

  gemm128_mainloop(p.X[z], p.W[z][wi], m0, n0, DMODEL, ldsA, ldsB, acc);

  const int tid = threadIdx.x, lane = tid & 63, wid = tid >> 6;
  const int wm = wid >> 1, wn = wid & 1, r = lane & 15, g = lane >> 4;
  const u16* bias = p.Bias[z][wi];
  u16* out = p.Out[z][wi];
  const float qscale = 0.125f * 1.4426950408889634f;  // 1/sqrt(dk) * log2(e)

#pragma unroll
  for (int j = 0; j < 4; ++j) {
    const int c = n0 + wn * 64 + j * 16 + r;          // output col in [0,512)
    const float bv = bf16_bits_to_f32(bias[c]);
    const int h = c >> 6, d = c & 63;
#pragma unroll
    for (int i = 0; i < 4; ++i) {
      const int row0 = m0 + wm * 64 + i * 16 + g * 4;
#pragma unroll
      for (int ii = 0; ii < 4; ++ii) {
        const int row = row0 + ii;                    // token index
        const int bb = row >> 10, ss = row & 1023;
        float v = acc[i][j][ii] + bv;
        size_t addr;
        if (wi == 0) {                                // Q: [B,H,S,64], scaled
          v *= qscale;
          addr = (((size_t)(bb * H_DIM + h)) * S_DIM + ss) * DK + d;
        } else if (wi == 1) {                         // K: [B,H,S,64]
          addr = (((size_t)(bb * H_DIM + h)) * S_DIM + ss) * DK + d;
        } else {                                      // V^T: [B,H,64,S]
          addr = (((size_t)(bb * H_DIM + h)) * DK + d) * S_DIM + ss;
        }
        out[addr] = f32_to_bf16_rne(v);
      }
    }
  }
}

// ---------------------------------------------------------------------------
// Kernel 2: merged-softmax attention. grid = (8, 64): x = 128-row Q tile,
// y = (b*8+h). 4 waves; wave w owns q rows [w*32, w*32+32).
// LDS tiles padded to 72-elem rows: 2-way bank aliasing only (free, m136).
// ---------------------------------------------------------------------------
struct AttnParams {
  const u16* Q[2];
  const u16* K[2];
  const u16* Vt[2];
  u16* O[2];
};

__device__ __forceinline__ void stage_tile64(const u16* __restrict__ g,
                                             int row_stride, u16* lds, int tid) {
#pragma unroll
  for (int j = 0; j < 2; ++j) {
    const int c = tid + j * 256;
    const int row = c >> 3;
    const int ch = (c & 7) * 8;
    *(short8*)&lds[row * 72 + ch] = *(const short8*)&g[(size_t)row * row_stride + ch];
  }
}

__global__ __launch_bounds__(256) void attn_merged(AttnParams p) {
  __shared__ u16 Ks[2][64 * 72];   // [stream][key][d pad72]
  __shared__ u16 Vs[2][64 * 72];   // [stream][d][key pad72]  (V^T tile)
  __shared__ u16 Ps[128 * 72];     // merged probs [q][key pad72]

  const int tid = threadIdx.x;
  const int lane = tid & 63;
  const int wid = tid >> 6;
  const int r = lane & 15, g = lane >> 4;
  const int bh = blockIdx.y;
  const int q0 = blockIdx.x * 128;
  const size_t hbase = (size_t)bh * S_DIM * DK;

  // Q fragments (A-operand): lane holds Q[row = q0+w*32+mt*16+(l&15)][k = kc*32+(l>>4)*8+j]
  short8 qf[2][2][2];
#pragma unroll
  for (int s = 0; s < 2; ++s)
#pragma unroll
    for (int mt = 0; mt < 2; ++mt)
#pragma unroll
      for (int kc = 0; kc < 2; ++kc) {
        const int row = q0 + wid * 32 + mt * 16 + r;
        qf[s][mt][kc] =
            *(const short8*)&p.Q[s][hbase + (size_t)row * DK + kc * 32 + g * 8];
      }

  float sums[2][2][4];
#pragma unroll
  for (int s = 0; s < 2; ++s)
#pragma unroll
    for (int mt = 0; mt < 2; ++mt)
#pragma unroll
      for (int i = 0; i < 4; ++i) sums[s][mt][i] = 0.f;

  // ---- pass 1: per-row sums of 2^score for both streams ----
  for (int kt = 0; kt < 16; ++kt) {
    const int k0 = kt * 64;
    if (kt) __syncthreads();
    stage_tile64(p.K[0] + hbase + (size_t)k0 * DK, DK, Ks[0], tid);
    stage_tile64(p.K[1] + hbase + (size_t)k0 * DK, DK, Ks[1], tid);
    __syncthreads();
#pragma unroll
    for (int s = 0; s < 2; ++s) {
#pragma unroll
      for (int nt = 0; nt < 4; ++nt) {
        const short8 b0 = *(const short8*)&Ks[s][(nt * 16 + r) * 72 + g * 8];
        const short8 b1 = *(const short8*)&Ks[s][(nt * 16 + r) * 72 + 32 + g * 8];
#pragma unroll
        for (int mt = 0; mt < 2; ++mt) {
          floatx4 acc = {0.f, 0.f, 0.f, 0.f};
          acc = mfma_bf16(qf[s][mt][0], b0, acc);
          acc = mfma_bf16(qf[s][mt][1], b1, acc);
#pragma unroll
          for (int i = 0; i < 4; ++i)
            sums[s][mt][i] += __builtin_amdgcn_exp2f(acc[i]);
        }
      }
    }
  }

  // reduce row sums across the 16 col-lanes; lane keeps rows g*4+i.
  float inv[2][2][4];
#pragma unroll
  for (int s = 0; s < 2; ++s)
#pragma unroll
    for (int mt = 0; mt < 2; ++mt)
#pragma unroll
      for (int i = 0; i < 4; ++i) {
        float v = sums[s][mt][i];
        v += __shfl_xor(v, 1);
        v += __shfl_xor(v, 2);
        v += __shfl_xor(v, 4);
        v += __shfl_xor(v, 8);
        inv[s][mt][i] = 1.0f / v;
      }

  floatx4 o[2][2][4];
  const floatx4 z4 = {0.f, 0.f, 0.f, 0.f};
#pragma unroll
  for (int s = 0; s < 2; ++s)
#pragma unroll
    for (int mt = 0; mt < 2; ++mt)
#pragma unroll
      for (int nt = 0; nt < 4; ++nt) o[s][mt][nt] = z4;

  // ---- pass 2: recompute scores, p = max(softmax_r, softmax_f), O += P@V ----
  for (int kt = 0; kt < 16; ++kt) {
    const int k0 = kt * 64;
    __syncthreads();
    stage_tile64(p.K[0] + hbase + (size_t)k0 * DK, DK, Ks[0], tid);
    stage_tile64(p.K[1] + hbase + (size_t)k0 * DK, DK, Ks[1], tid);
    stage_tile64(p.Vt[0] + hbase + k0, S_DIM, Vs[0], tid);
    stage_tile64(p.Vt[1] + hbase + k0, S_DIM, Vs[1], tid);
    __syncthreads();

#pragma unroll
    for (int nt = 0; nt < 4; ++nt) {
      const short8 br0 = *(const short8*)&Ks[0][(nt * 16 + r) * 72 + g * 8];
      const short8 br1 = *(const short8*)&Ks[0][(nt * 16 + r) * 72 + 32 + g * 8];
      const short8 bf0 = *(const short8*)&Ks[1][(nt * 16 + r) * 72 + g * 8];
      const short8 bf1 = *(const short8*)&Ks[1][(nt * 16 + r) * 72 + 32 + g * 8];
#pragma unroll
      for (int mt = 0; mt < 2; ++mt) {
        floatx4 ar = {0.f, 0.f, 0.f, 0.f};
        floatx4 af = {0.f, 0.f, 0.f, 0.f};
        ar = mfma_bf16(qf[0][mt][0], br0, ar);
        ar = mfma_bf16(qf[0][mt][1], br1, ar);
        af = mfma_bf16(qf[1][mt][0], bf0, af);
        af = mfma_bf16(qf[1][mt][1], bf1, af);
        const int prow = wid * 32 + mt * 16 + g * 4;
#pragma unroll
        for (int i = 0; i < 4; ++i) {
          const float pr = __builtin_amdgcn_exp2f(ar[i]) * inv[0][mt][i];
          const float pf = __builtin_amdgcn_exp2f(af[i]) * inv[1][mt][i];
          Ps[(prow + i) * 72 + nt * 16 + r] = f32_to_bf16_rne(fmaxf(pr, pf));
        }
      }
    }

    __syncthreads();   // force Ps write/read ordering across the type-punned DS ops

    // PV: P rows in A-layout, V^T cols in B-layout.
#pragma unroll
    for (int mt = 0; mt < 2; ++mt) {
      const short8 pa0 = *(const short8*)&Ps[(wid * 32 + mt * 16 + r) * 72 + g * 8];
      const short8 pa1 = *(const short8*)&Ps[(wid * 32 + mt * 16 + r) * 72 + 32 + g * 8];
#pragma unroll
      for (int s = 0; s < 2; ++s)
#pragma unroll
        for (int nt = 0; nt < 4; ++nt) {
          const short8 v0 = *(const short8*)&Vs[s][(nt * 16 + r) * 72 + g * 8];
          const short8 v1 = *(const short8*)&Vs[s][(nt * 16 + r) * 72 + 32 + g * 8];
          o[s][mt][nt] = mfma_bf16(pa0, v0, o[s][mt][nt]);
          o[s][mt][nt] = mfma_bf16(pa1, v1, o[s][mt][nt]);
        }
    }
  }

  // write O: [B,S,512] bf16 (heads concatenated -> flat rows for out-proj).
  const int bb = bh >> 3, h = bh & 7;
#pragma unroll
  for (int s = 0; s < 2; ++s) {
    u16* out = p.O[s];
#pragma unroll
    for (int mt = 0; mt < 2; ++mt)
#pragma unroll
      for (int nt = 0; nt < 4; ++nt) {
        const int col = h * 64 + nt * 16 + r;
#pragma unroll
        for (int i = 0; i < 4; ++i) {
          const int row = q0 + wid * 32 + mt * 16 + g * 4 + i;
          out[((size_t)bb * S_DIM + row) * DMODEL + col] =
              f32_to_bf16_rne(o[s][mt][nt][i]);
        }
      }
  }
}

// ---------------------------------------------------------------------------
// Kernel 3: output projections. grid = (64, 4, 2). Writes FP32 into d_out.
// ---------------------------------------------------------------------------
struct OutParams {
  const u16* A[2];
  const u16* W[2];
  const u16* Bias[2];
  float* Out[2];
};

__global__ __launch_bounds__(256) void out_gemm(OutParams p) {
  __shared__ u16 ldsA[128 * 32];
  __shared__ u16 ldsB[128 * 32];
  const int z = blockIdx.z;
  const int m0 = blockIdx.x * 128;
  const int n0 = blockIdx.y * 128;

  floatx4 acc[4][4];
  const floatx4 z4 = {0.f, 0.f, 0.f, 0.f};
#pragma unroll
  for (int i = 0; i < 4; ++i)
#pragma unroll
    for (int j = 0; j < 4; ++j) acc[i][j] = z4;

  gemm128_mainloop(p.A[z], p.W[z], m0, n0, DMODEL, ldsA, ldsB, acc);

  const int tid = threadIdx.x, lane = tid & 63, wid = tid >> 6;
  const int wm = wid >> 1, wn = wid & 1, r = lane & 15, g = lane >> 4;
  const u16* bias = p.Bias[z];
  float* out = p.Out[z];

#pragma unroll
  for (int j = 0; j < 4; ++j) {
    const int c = n0 + wn * 64 + j * 16 + r;
    const float bv = bf16_bits_to_f32(bias[c]);
#pragma unroll
    for (int i = 0; i < 4; ++i) {
      const int row0 = m0 + wm * 64 + i * 16 + g * 4;
#pragma unroll
      for (int ii = 0; ii < 4; ++ii)
        out[(size_t)(row0 + ii) * DMODEL + c] = acc[i][j][ii] + bv;   // FP32 store
    }
  }
}

// ---------------------------------------------------------------------------
extern "C" void kernel_launch(void* const* d_in, const int* in_sizes, int n_in,
                              void* d_out, int out_size, void* d_ws, size_t ws_size,
                              hipStream_t stream) {
  (void)in_sizes; (void)n_in; (void)out_size; (void)ws_size;
  u16* ws = (u16*)d_ws;
  u16* Qr = ws + 0 * SEG;
  u16* Kr = ws + 1 * SEG;
  u16* Vr = ws + 2 * SEG;   // stored transposed [B,H,64,S]
  u16* Qf = ws + 3 * SEG;
  u16* Kf = ws + 4 * SEG;
  u16* Vf = ws + 5 * SEG;   // stored transposed [B,H,64,S]
  u16* Or = ws + 6 * SEG;   // also holds converted X_rgb before attn overwrites
  u16* Of = ws + 7 * SEG;   // also holds converted X_flow
  u16* cW = ws + 8 * SEG;            // 8 x 262144
  u16* cB = cW + 8 * WSEG;           // 8 x 512

  // ---- conversion pre-pass ----
  ConvParams cp;
  int coff = 0;
  for (int i = 0; i < NT_CONV; ++i) {
    cp.src[i] = d_in[i];
    int n;
    if (i < 2) {
      n = (int)SEG;
      cp.dst[i] = (i == 0) ? Or : Of;
    } else {
      const int k = (i - 2) >> 1;
      const int isb = (i - 2) & 1;
      n = isb ? DMODEL : (int)WSEG;
      cp.dst[i] = isb ? (cB + k * DMODEL) : (cW + k * WSEG);
    }
    cp.n[i] = n;
    cp.coff[i] = coff;
    coff += (n + 65535) / 65536;
  }
  cp.coff[NT_CONV] = coff;   // 168 chunks total
  convert_inputs<<<dim3(coff), dim3(256), 0, stream>>>(cp);

  // ---- QKV projections ----
  QkvParams qp;
  qp.X[0] = Or;
  qp.X[1] = Of;
  for (int s = 0; s < 2; ++s)
    for (int wi = 0; wi < 3; ++wi) {
      const int k = s * 3 + wi;
      qp.W[s][wi] = cW + k * WSEG;
      qp.Bias[s][wi] = cB + k * DMODEL;
    }
  qp.Out[0][0] = Qr; qp.Out[0][1] = Kr; qp.Out[0][2] = Vr;
  qp.Out[1][0] = Qf; qp.Out[1][1] = Kf; qp.Out[1][2] = Vf;
  qkv_gemm<<<dim3(64, 12, 2), dim3(256), 0, stream>>>(qp);

  // ---- merged attention (overwrites Or/Of with O) ----
  AttnParams ap;
  ap.Q[0] = Qr; ap.Q[1] = Qf;
  ap.K[0] = Kr; ap.K[1] = Kf;
  ap.Vt[0] = Vr; ap.Vt[1] = Vf;
  ap.O[0] = Or; ap.O[1] = Of;
  attn_merged<<<dim3(8, 64), dim3(256), 0, stream>>>(ap);

  // ---- output projections (fp32 out) ----
  OutParams op;
  op.A[0] = Or; op.A[1] = Of;
  op.W[0] = cW + 6 * WSEG; op.Bias[0] = cB + 6 * DMODEL;
  op.W[1] = cW + 7 * WSEG; op.Bias[1] = cB + 7 * DMODEL;
  op.Out[0] = (float*)d_out;
  op.Out[1] = (float*)d_out + SEG;
  out_gemm<<<dim3(64, 4, 2), dim3(256), 0, stream>>>(op);
}